// Round 9
// baseline (512.057 us; speedup 1.0000x reference)
//
#include <hip/hip_runtime.h>
#include <math.h>

#define NUM_TAGS 20000
#define BATCH 64
#define H4 1024
#define HD 256
#define NT1 20001   // NUM_TAGS + 1

__device__ __forceinline__ float gelu_exact(float x) {
    return 0.5f * x * (1.0f + erff(x * 0.7071067811865476f));
}

// 4-byte-aligned float4 (rows can be misaligned: ld=20001)
struct F4 { float x, y, z, w; };

// ---- async global->LDS (gfx950). LDS dest = wave-uniform base + lane*size.
typedef const __attribute__((address_space(1))) void* gp_t;
typedef __attribute__((address_space(3))) void* lp_t;
__device__ __forceinline__ void async_ld4(const float* g, float* lds_base) {
    __builtin_amdgcn_global_load_lds((gp_t)g, (lp_t)lds_base, 4, 0, 0);
}
__device__ __forceinline__ void async_ld16(const float* g, float* lds_base) {
    __builtin_amdgcn_global_load_lds((gp_t)g, (lp_t)lds_base, 16, 0, 0);
}

// ---------- fused: scatter(dedup) + LN1 stats + LN1 apply, all in LDS -------
__global__ __launch_bounds__(1024) void k_ln1_fused(const int* __restrict__ tags,
                                                    const float* __restrict__ fc,
                                                    const float* __restrict__ lng,
                                                    const float* __restrict__ lnb,
                                                    float* __restrict__ y) {
    __shared__ int hist[NUM_TAGS];
    __shared__ float ls[16], ls2[16], smu, srs;
    const int b = blockIdx.x, tid = threadIdx.x;

    for (int t = tid; t < NUM_TAGS; t += 1024) hist[t] = 0;
    __syncthreads();

    if (tid < 128) {
        const int* tp = tags + ((size_t)(b * 128 + tid) << 4);
        int t[16];
#pragma unroll
        for (int i = 0; i < 16; ++i) t[i] = tp[i];
#pragma unroll
        for (int i = 0; i < 16; ++i) {
            bool dup = false;
            for (int j = 0; j < i; ++j) dup = dup || (t[j] == t[i]);
            if (!dup) atomicAdd(&hist[t[i]], 1);
        }
    }
    __syncthreads();

    float s = 0.f, s2 = 0.f;
    for (int t = tid; t < NUM_TAGS; t += 1024) {
        float v = (float)hist[t];
        s += v; s2 += v * v;
    }
#pragma unroll
    for (int off = 32; off > 0; off >>= 1) {
        s  += __shfl_down(s, off);
        s2 += __shfl_down(s2, off);
    }
    int wave = tid >> 6;
    if ((tid & 63) == 0) { ls[wave] = s; ls2[wave] = s2; }
    __syncthreads();
    if (tid == 0) {
        float S = 0.f, S2 = 0.f;
#pragma unroll
        for (int i = 0; i < 16; ++i) { S += ls[i]; S2 += ls2[i]; }
        float mu = S / (float)NUM_TAGS;
        float var = S2 / (float)NUM_TAGS - mu * mu;
        smu = mu;
        srs = rsqrtf(var + 1e-5f);
    }
    __syncthreads();
    float mu = smu, rs = srs;

    float* yrow = y + (size_t)b * NT1;
    if (tid == 0) yrow[0] = fc[b] * 0.01f;
    for (int t = tid; t < NUM_TAGS; t += 1024) {
        float v = (float)hist[t];
        yrow[1 + t] = (v - mu) * rs * lng[t] + lnb[t];
    }
}

// ---------------- round-5 GEMM (proven 315us config) + optional direct epi --
// P[(bx*gridDim.y+ky)][64][128] = A[64, kslice] @ W[kslice, 128cols]
// 256 thr: tn=tid&15 (cols tn*4..+3 and 64+tn*4..+3), tb=tid>>4 (4 rows each).
// BK=8, 4 LDS buffers (NBUF=4 required: skew (c+2)-(c-1)=3 != 0 mod 4; NBUF=3
// raced in round 7), depth-2 prefetch, counted vmcnt.
// A LDS layout [k4][row][klo]: float4 A-read per wave = 4 distinct addrs
// (16-lane broadcast each), banks 16tb+4i -> 2-way, free (m136).
// W read split-col tn*4 / 64+tn*4 -> 2-way distinct-addr, free.
// Requires: kpb % 8 == 0, kpb*gridDim.y == K (all slices full).
// PATH 0: W rows 16B-aligned (ldw%4==0, N%128==0): 1 async_ld16/thr/chunk.
// PATH 1: dword W loads, col clamped to N-1 (odd ldw): 4 async_ld4/thr/chunk.
// L per chunk: PATH0 = 2(A)+1(W) = 3; PATH1 = 2(A)+4(W) = 6.
// DIRECT=1: skip arena; write C[row*N + cn] = acc + bias[cn], guarded cn<N
// (ldc == N, odd ok -> scalar stores).
// launch_bounds(256,2): (256,4) forced 64 VGPR -> 94 MB spill (round 1).
template <int PATH, int DIRECT>
__global__ __launch_bounds__(256, 2) void k_gemm(const float* __restrict__ A, int lda,
                                                 const float* __restrict__ W, int ldw,
                                                 float* __restrict__ P,
                                                 int N, int kpb,
                                                 const float* __restrict__ bias) {
    __shared__ __align__(16) float As[4][512];    // [k4][row][klo]
    __shared__ __align__(16) float Ws[4][1024];   // [kk][col] : kk*128 + col
    const int tid = threadIdx.x;
    const int lane = tid & 63, wid = tid >> 6;
    const int tn = tid & 15, tb = tid >> 4;
    const int n0 = blockIdx.x * 128;
    const int kstart = blockIdx.y * kpb;
    const int nchunk = kpb >> 3;

    float acc[4][8];
#pragma unroll
    for (int i = 0; i < 4; ++i)
#pragma unroll
        for (int j = 0; j < 8; ++j) acc[i][j] = 0.f;

    // ---- issue chunk c into buffer b (async DMA) ----
    auto issue = [&](int b, int c) {
        int k0 = kstart + c * 8;
        // A tile: 64 rows x 8 kk = 512 dwords; d -> k4=d>>8, row=(d&255)>>2,
        // klo=d&3  (dest layout As[k4][row][klo], contiguous in d)
#pragma unroll
        for (int j = 0; j < 2; ++j) {
            int d0 = j * 256 + wid * 64;
            int d = d0 + lane;
            int k4 = d >> 8, row = (d & 255) >> 2, klo = d & 3;
            async_ld4(A + (size_t)row * lda + k0 + k4 * 4 + klo, &As[b][d0]);
        }
        if (PATH == 0) {
            // W tile: 8 rows x 128 cols = 256 16B-granules; g=tid -> kk=g>>5, c4=g&31
            int kk = tid >> 5, c4 = tid & 31;
            async_ld16(W + (size_t)(k0 + kk) * ldw + n0 + c4 * 4, &Ws[b][wid * 256]);
        } else {
            // W tile: 1024 dwords; d -> kk=d>>7, cc=d&127 (col clamped)
#pragma unroll
            for (int j = 0; j < 4; ++j) {
                int d = j * 256 + tid;
                int kk = d >> 7, cc = d & 127;
                async_ld4(W + (size_t)(k0 + kk) * ldw + min(n0 + cc, N - 1),
                          &Ws[b][j * 256 + wid * 64]);
            }
        }
    };

    issue(0, 0);
    if (nchunk > 1) issue(1, 1);

    for (int c = 0; c < nchunk; ++c) {
        if (c + 2 < nchunk) issue((c + 2) & 3, c + 2);
        // Counted wait: keep up to 2 chunks' loads in flight across the barrier.
        int ahead = nchunk - 1 - c;
        if (PATH == 0) {
            if (ahead >= 2)      asm volatile("s_waitcnt vmcnt(6)"  ::: "memory");
            else if (ahead == 1) asm volatile("s_waitcnt vmcnt(3)"  ::: "memory");
            else                 asm volatile("s_waitcnt vmcnt(0)"  ::: "memory");
        } else {
            if (ahead >= 2)      asm volatile("s_waitcnt vmcnt(12)" ::: "memory");
            else if (ahead == 1) asm volatile("s_waitcnt vmcnt(6)"  ::: "memory");
            else                 asm volatile("s_waitcnt vmcnt(0)"  ::: "memory");
        }
        __builtin_amdgcn_s_barrier();          // all waves' chunk-c loads landed
        asm volatile("" ::: "memory");         // no LDS access hoisted above

        const float* Ab = As[c & 3];
        const float* Wb = Ws[c & 3];
        __builtin_amdgcn_s_setprio(1);
#pragma unroll
        for (int k4 = 0; k4 < 2; ++k4) {
            float4 a4[4];
#pragma unroll
            for (int i = 0; i < 4; ++i)
                a4[i] = *(const float4*)&Ab[k4 * 256 + (tb * 4 + i) * 4];
#pragma unroll
            for (int kl = 0; kl < 4; ++kl) {
                const float4 w0 = *(const float4*)&Wb[(k4 * 4 + kl) * 128 + tn * 4];
                const float4 w1 = *(const float4*)&Wb[(k4 * 4 + kl) * 128 + 64 + tn * 4];
#pragma unroll
                for (int i = 0; i < 4; ++i) {
                    float av = (kl == 0) ? a4[i].x : (kl == 1) ? a4[i].y
                             : (kl == 2) ? a4[i].z : a4[i].w;
                    acc[i][0] = fmaf(av, w0.x, acc[i][0]);
                    acc[i][1] = fmaf(av, w0.y, acc[i][1]);
                    acc[i][2] = fmaf(av, w0.z, acc[i][2]);
                    acc[i][3] = fmaf(av, w0.w, acc[i][3]);
                    acc[i][4] = fmaf(av, w1.x, acc[i][4]);
                    acc[i][5] = fmaf(av, w1.y, acc[i][5]);
                    acc[i][6] = fmaf(av, w1.z, acc[i][6]);
                    acc[i][7] = fmaf(av, w1.w, acc[i][7]);
                }
            }
        }
        __builtin_amdgcn_s_setprio(0);
        asm volatile("" ::: "memory");         // no LDS access sunk below
    }

    if (DIRECT) {
        // direct write: C[row][cn] = acc + bias[cn], ldc == N (odd ok)
#pragma unroll
        for (int i = 0; i < 4; ++i) {
            int row = tb * 4 + i;
            float* crow = P + (size_t)row * N;
#pragma unroll
            for (int jj = 0; jj < 4; ++jj) {
                int cn = n0 + tn * 4 + jj;
                if (cn < N) crow[cn] = acc[i][jj] + bias[cn];
            }
#pragma unroll
            for (int jj = 0; jj < 4; ++jj) {
                int cn = n0 + 64 + tn * 4 + jj;
                if (cn < N) crow[cn] = acc[i][4 + jj] + bias[cn];
            }
        }
    } else {
        float* Pp = P + ((size_t)blockIdx.x * gridDim.y + blockIdx.y) * 8192;
#pragma unroll
        for (int i = 0; i < 4; ++i) {
            int row = tb * 4 + i;
            float4 v0 = {acc[i][0], acc[i][1], acc[i][2], acc[i][3]};
            float4 v1 = {acc[i][4], acc[i][5], acc[i][6], acc[i][7]};
            *(float4*)&Pp[row * 128 + tn * 4]      = v0;
            *(float4*)&Pp[row * 128 + 64 + tn * 4] = v1;
        }
    }
}

// ------- fused: reduce GEMM1 partials + bias + rank1(fc) + gelu + LN2 ------
__global__ __launch_bounds__(1024) void k_red_ln2(const float* __restrict__ P, int KS,
                                                  const float* __restrict__ bias,
                                                  const float* __restrict__ r1row,
                                                  const float* __restrict__ fc,
                                                  const float* __restrict__ lng,
                                                  const float* __restrict__ lnb,
                                                  float* __restrict__ h2) {
    const int b = blockIdx.x, n = threadIdx.x;
    int nb = n >> 7, col = n & 127;
    const float* p = P + (size_t)nb * KS * 8192 + b * 128 + col;
    float s0 = 0.f, s1 = 0.f, s2v = 0.f, s3 = 0.f;
    int k = 0;
    for (; k + 3 < KS; k += 4) {
        s0  += p[(size_t)(k + 0) * 8192];
        s1  += p[(size_t)(k + 1) * 8192];
        s2v += p[(size_t)(k + 2) * 8192];
        s3  += p[(size_t)(k + 3) * 8192];
    }
    for (; k < KS; ++k) s0 += p[(size_t)k * 8192];
    float v = (s0 + s1) + (s2v + s3) + bias[n] + fc[b] * 0.01f * r1row[n];
    v = gelu_exact(v);

    float s = v, s2 = v * v;
#pragma unroll
    for (int off = 32; off > 0; off >>= 1) {
        s  += __shfl_down(s, off);
        s2 += __shfl_down(s2, off);
    }
    __shared__ float ls[16], ls2[16], smu, srs;
    int wave = n >> 6;
    if ((n & 63) == 0) { ls[wave] = s; ls2[wave] = s2; }
    __syncthreads();
    if (n == 0) {
        float S = 0.f, S2 = 0.f;
#pragma unroll
        for (int i = 0; i < 16; ++i) { S += ls[i]; S2 += ls2[i]; }
        float mu = S / (float)H4;
        float var = S2 / (float)H4 - mu * mu;
        smu = mu;
        srs = rsqrtf(var + 1e-5f);
    }
    __syncthreads();
    h2[(size_t)b * H4 + n] = (v - smu) * srs * lng[n] + lnb[n];
}

// ------- mid GEMM, fused bias(+gelu), no split-K, no arena -----------------
// out[row, c] = act(A[row,:K] @ W[:,c] + bias[c]).  One block = (row, 256-col
// slab). A-row address is wave-uniform -> compiler scalarizes (SMEM/broadcast);
// W[k*N+c] coalesced across lanes (64 consecutive dwords per k). 8-deep inner
// unroll gives 8 outstanding W loads. M=64 rows x (N/256) slabs blocks.
template <bool GELU>
__global__ __launch_bounds__(256) void k_mid(const float* __restrict__ A, int K,
                                             const float* __restrict__ W, int N,
                                             const float* __restrict__ bias,
                                             float* __restrict__ out, int ldo) {
    const int row = blockIdx.y;
    const int c = blockIdx.x * 256 + threadIdx.x;
    const float* Arow = A + (size_t)row * K;
    const float* Wc = W + c;
    float acc0 = 0.f, acc1 = 0.f;
    for (int k0 = 0; k0 < K; k0 += 8) {
        float4 a0 = *(const float4*)&Arow[k0];
        float4 a1 = *(const float4*)&Arow[k0 + 4];
        float w0 = Wc[(size_t)(k0 + 0) * N];
        float w1 = Wc[(size_t)(k0 + 1) * N];
        float w2 = Wc[(size_t)(k0 + 2) * N];
        float w3 = Wc[(size_t)(k0 + 3) * N];
        float w4 = Wc[(size_t)(k0 + 4) * N];
        float w5 = Wc[(size_t)(k0 + 5) * N];
        float w6 = Wc[(size_t)(k0 + 6) * N];
        float w7 = Wc[(size_t)(k0 + 7) * N];
        acc0 = fmaf(a0.x, w0, acc0);
        acc1 = fmaf(a0.y, w1, acc1);
        acc0 = fmaf(a0.z, w2, acc0);
        acc1 = fmaf(a0.w, w3, acc1);
        acc0 = fmaf(a1.x, w4, acc0);
        acc1 = fmaf(a1.y, w5, acc1);
        acc0 = fmaf(a1.z, w6, acc0);
        acc1 = fmaf(a1.w, w7, acc1);
    }
    float v = acc0 + acc1 + bias[c];
    if (GELU) v = gelu_exact(v);
    out[(size_t)row * ldo + c] = v;
}

// ---------------- launch ----------------
extern "C" void kernel_launch(void* const* d_in, const int* in_sizes, int n_in,
                              void* d_out, int out_size, void* d_ws, size_t ws_size,
                              hipStream_t stream) {
    (void)in_sizes; (void)n_in; (void)out_size;
    const int*   tags  = (const int*)d_in[0];
    const float* fc    = (const float*)d_in[1];
    const float* ln_g  = (const float*)d_in[2];
    const float* ln_b  = (const float*)d_in[3];
    const float* w1    = (const float*)d_in[4];
    const float* b1    = (const float*)d_in[5];
    const float* ln2_g = (const float*)d_in[6];
    const float* ln2_b = (const float*)d_in[7];
    const float* we1   = (const float*)d_in[8];
    const float* be1   = (const float*)d_in[9];
    const float* we2   = (const float*)d_in[10];
    const float* be2   = (const float*)d_in[11];
    const float* wd1   = (const float*)d_in[12];
    const float* bd1   = (const float*)d_in[13];
    const float* wd2   = (const float*)d_in[14];
    const float* bd2   = (const float*)d_in[15];

    float* out = (float*)d_out;
    float* y   = out;                              // 64*20001
    float* enc = out + (size_t)BATCH * NT1;        // 64*256
    float* dec = enc + BATCH * HD;                 // 64*20001

    char* ws = (char*)d_ws;
    size_t off = 0;
    float* h2     = (float*)(ws + off); off += (size_t)BATCH * H4 * 4;
    float* g2     = (float*)(ws + off); off += (size_t)BATCH * H4 * 4;
    float* dd     = (float*)(ws + off); off += (size_t)BATCH * H4 * 4;
    float* arena  = (float*)(ws + off);
    size_t avail  = (ws_size > off) ? (ws_size - off) : 0;

    // GEMM1 split-K tier (ws_size constant across calls -> deterministic).
    // kpb1=160/KS=125 -> arena 8*125*8192*4 = 32.8 MB; fallback 400/50 = 13 MB.
    const size_t MB = 1024 * 1024;
    int kpb1, KS1;
    if (avail >= 33 * MB) { kpb1 = 160; KS1 = 125; }
    else                  { kpb1 = 400; KS1 = 50;  }

    // 1) fused scatter + LN1 (LDS histogram)
    k_ln1_fused<<<64, 1024, 0, stream>>>(tags, fc, ln_g, ln_b, y);

    // 2) GEMM1: yn[64,20000] @ w1[1:,1024] -> arena partials
    k_gemm<1, 0><<<dim3(8, KS1), 256, 0, stream>>>(y + 1, NT1, w1 + H4, H4,
                                                   arena, H4, kpb1, nullptr);
    // 3) reduce + bias + rank1(fc)*w1row0 + gelu + LN2 -> h2
    k_red_ln2<<<64, 1024, 0, stream>>>(arena, KS1, b1, w1, fc, ln2_g, ln2_b, h2);

    // 4) g2 = gelu(h2 @ we1 + be1)
    k_mid<true><<<dim3(4, 64), 256, 0, stream>>>(h2, H4, we1, H4, be1, g2, H4);
    // 5) enc = g2 @ we2 + be2
    k_mid<false><<<dim3(1, 64), 256, 0, stream>>>(g2, H4, we2, HD, be2, enc, HD);
    // 6) dd = gelu(enc @ wd1 + bd1)
    k_mid<true><<<dim3(4, 64), 256, 0, stream>>>(enc, HD, wd1, H4, bd1, dd, H4);

    // 7) GEMM5 direct: dec = dd @ wd2 + bd2 (odd ldw -> PATH 1; no arena)
    k_gemm<1, 1><<<dim3(157, 1), 256, 0, stream>>>(dd, H4, wd2, NT1,
                                                   dec, NT1, H4, bd2);
}